// Round 9
// baseline (428.819 us; speedup 1.0000x reference)
//
#include <hip/hip_runtime.h>
#include <hip/hip_bf16.h>

#define SS 2048
#define BB 16
#define DD 512

typedef __attribute__((ext_vector_type(4))) float f32x4;
typedef __attribute__((ext_vector_type(8))) short bf16x8;
typedef __attribute__((ext_vector_type(4))) unsigned short us4;
typedef unsigned short us;

#define MFMA16(a,b,c) __builtin_amdgcn_mfma_f32_16x16x32_bf16((a),(b),(c),0,0,0)
#define BAR() __builtin_amdgcn_s_barrier()
#define WAITV(n) asm volatile("s_waitcnt vmcnt(" #n ")" ::: "memory")
#define WAITL()  asm volatile("s_waitcnt lgkmcnt(0)" ::: "memory")

__device__ __forceinline__ unsigned short f2b(float f) {
    union { float f; unsigned u; } v; v.f = f;
    unsigned r = v.u + 0x7FFFu + ((v.u >> 16) & 1u);
    return (unsigned short)(r >> 16);
}

// 256B-row LDS tile, 4-bit XOR swizzle
__device__ __forceinline__ bf16x8 ldfrag8(const us* base, int row, int kelem) {
    int off = (row << 8) + (kelem << 1);
    off ^= (row & 15) << 4;
    return *(const bf16x8*)((const char*)base + off);
}
// 512B-row LDS tile, swizzle (row&15)<<5 (2-way/free)
__device__ __forceinline__ bf16x8 ldfrag9(const us* base, int row, int kelem) {
    int off = (row << 9) + (kelem << 1);
    off ^= (row & 15) << 5;
    return *(const bf16x8*)((const char*)base + off);
}
// 128B-row (k_gemm)
__device__ __forceinline__ bf16x8 ldfrag(const us* base, int row, int kelem, int rowshift) {
    int off = (row << rowshift) + (kelem << 1);
    off ^= (row & 7) << 4;
    return *(const bf16x8*)((const char*)base + off);
}

__device__ __forceinline__ void gl16(const void* g, void* l) {
    __builtin_amdgcn_global_load_lds(
        (const __attribute__((address_space(1))) unsigned*)g,
        (__attribute__((address_space(3))) unsigned*)l, 16, 0, 0);
}

// ---------------------------------------------------------------------------
// Prep: seq [S][B][D] fp32 -> Xb [B][S][D] bf16 and Xbt [B][D][S] bf16.
// ---------------------------------------------------------------------------
__global__ __launch_bounds__(256) void k_prep_x(const float* __restrict__ seq,
        us* __restrict__ Xb, us* __restrict__ Xbt) {
    __shared__ __align__(16) char L[64 * 128];
    const int tid = threadIdx.x;
    const int d0 = blockIdx.x * 64, s0 = blockIdx.y * 64, b = blockIdx.z;
    {
        int r = tid >> 2, seg = (tid & 3) * 16;
        const float* src = seq + (size_t)(s0 + r) * (BB * DD) + (size_t)b * DD + d0 + seg;
        __align__(16) us vals[16];
        #pragma unroll
        for (int q = 0; q < 4; ++q) {
            f32x4 v = *(const f32x4*)(src + q * 4);
            vals[q*4+0] = f2b(v.x); vals[q*4+1] = f2b(v.y);
            vals[q*4+2] = f2b(v.z); vals[q*4+3] = f2b(v.w);
        }
        us* xo = Xb + ((size_t)b * SS + s0 + r) * DD + d0 + seg;
        *(bf16x8*)xo       = *(bf16x8*)&vals[0];
        *(bf16x8*)(xo + 8) = *(bf16x8*)&vals[8];
        #pragma unroll
        for (int j = 0; j < 16; ++j) {
            int d = seg + j;
            int addr = (d * 128 + r * 2) ^ ((d & 7) << 4);
            *(us*)(L + addr) = vals[j];
        }
    }
    __syncthreads();
    {
        int d = tid >> 2, sseg = (tid & 3) * 16;
        int c = (d & 7) << 4;
        int base = d * 128 + sseg * 2;
        bf16x8 h0 = *(bf16x8*)(L + (base ^ c));
        bf16x8 h1 = *(bf16x8*)(L + ((base + 16) ^ c));
        us* o = Xbt + ((size_t)b * DD + d0 + d) * SS + s0 + sseg;
        *(bf16x8*)o       = h0;
        *(bf16x8*)(o + 8) = h1;
    }
}

// ---------------------------------------------------------------------------
// Gt[p][i] = (1/sqrt(D)) * sum_a Wv[a,i] * Wq[a,p]
// ---------------------------------------------------------------------------
__global__ __launch_bounds__(256) void k_prepG(const float* __restrict__ Wv,
        const float* __restrict__ Wq, us* __restrict__ Gt) {
    __shared__ float Sq[32][64], Sv[32][64];
    const int tid = threadIdx.x;
    const int p0 = blockIdx.x * 64, i0 = blockIdx.y * 64;
    const int tp = tid & 15, ti = tid >> 4;
    float acc[4][4] = {};
    for (int a0 = 0; a0 < DD; a0 += 32) {
        #pragma unroll
        for (int j = 0; j < 2; ++j) {
            int slot = tid + j * 256;
            int row = slot >> 4, c4 = (slot & 15) * 4;
            *(f32x4*)&Sq[row][c4] = *(const f32x4*)(Wq + (size_t)(a0 + row) * DD + p0 + c4);
            *(f32x4*)&Sv[row][c4] = *(const f32x4*)(Wv + (size_t)(a0 + row) * DD + i0 + c4);
        }
        __syncthreads();
        for (int a = 0; a < 32; ++a) {
            f32x4 q = *(f32x4*)&Sq[a][tp * 4];
            f32x4 v = *(f32x4*)&Sv[a][ti * 4];
            #pragma unroll
            for (int x = 0; x < 4; ++x)
                #pragma unroll
                for (int y = 0; y < 4; ++y)
                    acc[x][y] += q[x] * v[y];
        }
        __syncthreads();
    }
    const float sc = 0.044194173824159216f;
    #pragma unroll
    for (int x = 0; x < 4; ++x)
        #pragma unroll
        for (int y = 0; y < 4; ++y)
            Gt[(size_t)(p0 + tp * 4 + x) * DD + i0 + ti * 4 + y] = f2b(acc[x][y] * sc);
}

// u[p] = (1/sqrt(D)) * sum_a bv[a] * Wq[a,p]
__global__ __launch_bounds__(512) void k_prepU(const float* __restrict__ Wq,
        const float* __restrict__ bv, float* __restrict__ u) {
    int p = threadIdx.x;
    float s = 0.f;
    for (int a0 = 0; a0 < DD; a0 += 8) {
        #pragma unroll
        for (int j = 0; j < 8; ++j)
            s += bv[a0 + j] * Wq[(size_t)(a0 + j) * DD + p];
    }
    u[p] = s * 0.044194173824159216f;
}

__global__ void k_prepW(const float* __restrict__ Wk, us* __restrict__ Wkb) {
    int i = (blockIdx.x * 256 + threadIdx.x) * 4;
    f32x4 v = *(const f32x4*)(Wk + i);
    us4 o; o.x = f2b(v.x); o.y = f2b(v.y); o.z = f2b(v.z); o.w = f2b(v.w);
    *(us4*)(Wkb + i) = o;
}

// ---------------------------------------------------------------------------
// bf16 GEMM: C[row,n] = sum_k A[row,k]*Bm[n,k] + bias[n]
// ---------------------------------------------------------------------------
template<int OUTMODE>
__global__ __launch_bounds__(256, 2) void k_gemm(
        const us* __restrict__ A, const us* __restrict__ Bm,
        const float* __restrict__ bias, void* __restrict__ outp) {
    __shared__ __align__(16) us As[2][128 * 64];
    __shared__ __align__(16) us Bs[2][128 * 64];
    const int tid = threadIdx.x;
    const int lane = tid & 63;
    const int w = tid >> 6;
    const int wr = w >> 1, wc = w & 1;
    const int l15 = lane & 15, lg = lane >> 4;
    const int b = blockIdx.x >> 4;
    const int s0 = (blockIdx.x & 15) * 128;
    const int n0 = blockIdx.y * 128;
    const char* abase = (const char*)(A + ((size_t)b * SS + s0) * DD);
    const char* bbase = (const char*)Bm + (size_t)n0 * 1024;

    f32x4 acc[4][4];
    #pragma unroll
    for (int m = 0; m < 4; ++m)
        #pragma unroll
        for (int n = 0; n < 4; ++n) acc[m][n] = (f32x4)(0.0f);

    auto stage = [&](int db, int p) {
        #pragma unroll
        for (int j = 0; j < 4; ++j) {
            int x = (tid + j * 256) * 16;
            int gx = x ^ (((x >> 7) & 7) << 4);
            int row = gx >> 7, col = gx & 127;
            gl16(abase + (size_t)row * 1024 + p * 128 + col, (char*)As[db] + x);
            gl16(bbase + (size_t)row * 1024 + p * 128 + col, (char*)Bs[db] + x);
        }
    };

    stage(0, 0);
    for (int p = 0; p < 8; ++p) {
        if (p < 7) { stage((p + 1) & 1, p + 1); WAITV(8); }
        else       { WAITV(0); }
        BAR();
        const us* Ac = As[p & 1]; const us* Bc = Bs[p & 1];
        __builtin_amdgcn_s_setprio(1);
        #pragma unroll
        for (int kk = 0; kk < 2; ++kk) {
            bf16x8 af[4], bfr[4];
            #pragma unroll
            for (int m = 0; m < 4; ++m) af[m]  = ldfrag(Ac, 64 * wr + 16 * m + l15, kk * 32 + 8 * lg, 7);
            #pragma unroll
            for (int n = 0; n < 4; ++n) bfr[n] = ldfrag(Bc, 64 * wc + 16 * n + l15, kk * 32 + 8 * lg, 7);
            #pragma unroll
            for (int m = 0; m < 4; ++m)
                #pragma unroll
                for (int n = 0; n < 4; ++n)
                    acc[m][n] = MFMA16(af[m], bfr[n], acc[m][n]);
        }
        __builtin_amdgcn_s_setprio(0);
        BAR();
    }

    #pragma unroll
    for (int m = 0; m < 4; ++m) {
        #pragma unroll
        for (int n = 0; n < 4; ++n) {
            int col = n0 + 64 * wc + 16 * n + l15;
            float bia = bias[col];
            #pragma unroll
            for (int r = 0; r < 4; ++r) {
                int row = s0 + 64 * wr + 16 * m + 4 * lg + r;
                float v = acc[m][n][r] + bia;
                if (OUTMODE == 0)
                    ((us*)outp)[((size_t)b * SS + row) * DD + col] = f2b(v);
                else
                    ((float*)outp)[((size_t)row * BB + b) * DD + col] = v;
            }
        }
    }
}

// ---------------------------------------------------------------------------
// Flash attention v9: 64KB windows, 4 stall-points/step, 32 MFMA/cluster.
//   QB=64 (512 blocks), 8 waves = 4 rg (16 rows) x 2 cg.  M=16/wave.
//   af[16] (Vt, all k) in regs (64 VGPR).  accv[2][8]=64.  No VtL needed.
//   Per step (KV=128): windows w0=X[128t][k0:256], w1=X[128t][k256:512]
//   (512B rows), w2=XT[e0:256][128t], w3=XT[e256:512][128t] (256B rows);
//   2 alternating 64KB slots; 8 gl16/thread/window; WAITV(8) = 16 outstanding
//   -> oldest window complete.  Row-sums via ones-B MFMA (accv row layout).
// ---------------------------------------------------------------------------
__global__ __launch_bounds__(512, 2) void k_attn(
        const us* __restrict__ Vtb, const us* __restrict__ Xb,
        const us* __restrict__ Xbt, us* __restrict__ Ob) {
    __shared__ __align__(16) us XW[2][32768];    // 2 x 64KB window slots
    __shared__ __align__(16) us Pb[64 * 128];    // P [64 r][128 t], 16KB

    const int tid = threadIdx.x;
    const int lane = tid & 63;
    const int w = tid >> 6;
    const int rg = w & 3;          // rows 16*rg .. +15
    const int cg = w >> 2;         // QK: t-half 64*cg; PV: e-sub 128*cg
    const int l15 = lane & 15, lg = lane >> 4;

    const int wg = blockIdx.x;
    const int b  = wg & 15;        // XCD x owns batches {x, x+8}
    const int s0 = (wg >> 4) * 64;

    const char* vbase  = (const char*)(Vtb + ((size_t)b * SS + s0) * DD);
    const char* xabase = (const char*)(Xb  + (size_t)b * SS * DD);
    const char* xtbase = (const char*)(Xbt + (size_t)b * DD * SS);

    // X k-half window: [128 t-rows][256 k] = 64KB, 512B rows, swz (row&15)<<5
    auto issueX = [&](int h, int t0, us* dst0) {
        char* dst = (char*)dst0;
        #pragma unroll
        for (int j = 0; j < 8; ++j) {
            int x = tid * 16 + j * 8192;
            int gx = x ^ (((x >> 9) & 15) << 5);
            int row = gx >> 9, col = gx & 511;
            gl16(xabase + (size_t)(t0 + row) * 1024 + h * 512 + col, dst + x);
        }
    };
    // XT e-half window: [256 e-rows][128 t] = 64KB, 256B rows, swz (row&15)<<4
    auto issueT = [&](int h, int t0, us* dst0) {
        char* dst = (char*)dst0;
        #pragma unroll
        for (int j = 0; j < 8; ++j) {
            int x = tid * 16 + j * 8192;
            int gx = x ^ (((x >> 8) & 15) << 4);
            int row = gx >> 8, col = gx & 255;
            gl16(xtbase + (size_t)(h * 256 + row) * (SS * 2)
                        + (size_t)t0 * 2 + col, dst + x);
        }
    };

    // ---- prologue: Vt [64][512] via 4 x 16KB sub-chunks into XW[0] ----
    #pragma unroll
    for (int p = 0; p < 4; ++p) {
        #pragma unroll
        for (int j = 0; j < 2; ++j) {
            int x = tid * 16 + j * 8192;
            int gx = x ^ (((x >> 8) & 15) << 4);
            int row = gx >> 8, col = gx & 255;
            gl16(vbase + (size_t)row * 1024 + p * 256 + col,
                 (char*)XW[0] + p * 16384 + x);
        }
    }
    WAITV(0); BAR();
    bf16x8 af[16];                 // af[4p+kk] covers k = 128p + 32kk
    #pragma unroll
    for (int p = 0; p < 4; ++p)
        #pragma unroll
        for (int kk = 0; kk < 4; ++kk)
            af[4 * p + kk] = ldfrag8((const us*)XW[0] + p * 8192,
                                     16 * rg + l15, 32 * kk + 8 * lg);
    WAITL(); BAR();

    issueX(0, 0, XW[0]);
    issueX(1, 0, XW[1]);

    const short one_bf = (short)0x3F80;
    const bf16x8 ones = {one_bf, one_bf, one_bf, one_bf,
                         one_bf, one_bf, one_bf, one_bf};

    f32x4 accv[2][8];              // [e-half][nt], e = 256h + 128cg + 16nt
    #pragma unroll
    for (int h = 0; h < 2; ++h)
        #pragma unroll
        for (int nt = 0; nt < 8; ++nt) accv[h][nt] = (f32x4)(0.0f);
    f32x4 lsum = (f32x4)(0.0f);
    const int idx = 16 * rg + 4 * lg;

    for (int step = 0; step < 16; ++step) {
        const int t0 = step * 128;
        const int t0n = (t0 + 128) & (SS - 1);
        f32x4 sacc[4];
        #pragma unroll
        for (int nt = 0; nt < 4; ++nt) sacc[nt] = (f32x4)(0.0f);

        // ---- QK h=0 (slot0): 32 MFMA ----
        WAITV(8); BAR();
        __builtin_amdgcn_s_setprio(1);
        #pragma unroll
        for (int kk = 0; kk < 8; ++kk)
            #pragma unroll
            for (int nt = 0; nt < 4; ++nt) {
                bf16x8 bq = ldfrag9(XW[0], 64 * cg + 16 * nt + l15, 32 * kk + 8 * lg);
                sacc[nt] = MFMA16(af[kk], bq, sacc[nt]);
            }
        __builtin_amdgcn_s_setprio(0);
        BAR();
        issueT(0, t0, XW[0]);

        // ---- QK h=1 (slot1): 32 MFMA ----
        WAITV(8); BAR();
        __builtin_amdgcn_s_setprio(1);
        #pragma unroll
        for (int kk = 0; kk < 8; ++kk)
            #pragma unroll
            for (int nt = 0; nt < 4; ++nt) {
                bf16x8 bq = ldfrag9(XW[1], 64 * cg + 16 * nt + l15, 32 * kk + 8 * lg);
                sacc[nt] = MFMA16(af[8 + kk], bq, sacc[nt]);
            }
        __builtin_amdgcn_s_setprio(0);
        BAR();
        issueT(1, t0, XW[1]);

        // ---- softmax (static max): P = exp(s) -> Pb ----
        #pragma unroll
        for (int nt = 0; nt < 4; ++nt)
            #pragma unroll
            for (int ri = 0; ri < 4; ++ri)
                sacc[nt][ri] = __expf(sacc[nt][ri]);
        #pragma unroll
        for (int nt = 0; nt < 4; ++nt)
            #pragma unroll
            for (int ri = 0; ri < 4; ++ri) {
                int row = idx + ri;
                int col = 64 * cg + 16 * nt + l15;
                int off = ((row << 8) + (col << 1)) ^ ((row & 15) << 4);
                *(us*)((char*)Pb + off) = f2b(sacc[nt][ri]);
            }
        WAITL(); BAR();
        bf16x8 pa[4];
        #pragma unroll
        for (int kk = 0; kk < 4; ++kk)
            pa[kk] = ldfrag8(Pb, 16 * rg + l15, 32 * kk + 8 * lg);
        #pragma unroll
        for (int kk = 0; kk < 4; ++kk)
            lsum = MFMA16(pa[kk], ones, lsum);

        // ---- PV h=0 (slot0): 32 MFMA ----
        WAITV(8); BAR();
        __builtin_amdgcn_s_setprio(1);
        #pragma unroll
        for (int kk = 0; kk < 4; ++kk)
            #pragma unroll
            for (int nt = 0; nt < 8; ++nt) {
                bf16x8 bx = ldfrag8(XW[0], 128 * cg + 16 * nt + l15, 32 * kk + 8 * lg);
                accv[0][nt] = MFMA16(pa[kk], bx, accv[0][nt]);
            }
        __builtin_amdgcn_s_setprio(0);
        BAR();
        issueX(0, t0n, XW[0]);

        // ---- PV h=1 (slot1): 32 MFMA ----
        WAITV(8); BAR();
        __builtin_amdgcn_s_setprio(1);
        #pragma unroll
        for (int kk = 0; kk < 4; ++kk)
            #pragma unroll
            for (int nt = 0; nt < 8; ++nt) {
                bf16x8 bx = ldfrag8(XW[1], 128 * cg + 16 * nt + l15, 32 * kk + 8 * lg);
                accv[1][nt] = MFMA16(pa[kk], bx, accv[1][nt]);
            }
        __builtin_amdgcn_s_setprio(0);
        BAR();
        issueX(1, t0n, XW[1]);
    }

    // ---- epilogue: O' = accv / lsum (same row layout) -> bf16 ----
    us* orow = Ob + ((size_t)b * SS + s0) * DD;
    #pragma unroll
    for (int h = 0; h < 2; ++h)
        #pragma unroll
        for (int nt = 0; nt < 8; ++nt)
            #pragma unroll
            for (int ri = 0; ri < 4; ++ri) {
                int row = idx + ri;
                int e = 256 * h + 128 * cg + 16 * nt + l15;
                orow[(size_t)row * DD + e] = f2b(accv[h][nt][ri] / lsum[ri]);
            }
}

extern "C" void kernel_launch(void* const* d_in, const int* in_sizes, int n_in,
                              void* d_out, int out_size, void* d_ws, size_t ws_size,
                              hipStream_t stream) {
    const float* seq = (const float*)d_in[0];
    const float* Wv  = (const float*)d_in[1];
    const float* bv  = (const float*)d_in[2];
    const float* Wq  = (const float*)d_in[3];
    // d_in[4] = bq: softmax-row-constant -> unused
    const float* Wk  = (const float*)d_in[5];
    const float* bk  = (const float*)d_in[6];

    char* ws = (char*)d_ws;
    us*    Xb  = (us*)ws;                                  // [B][S][D] bf16, 32MB
    us*    Xbt = (us*)(ws + (size_t)33554432);             // [B][D][S] bf16, 32MB
    us*    Vtb = (us*)(ws + (size_t)67108864);             // [B][S][D] bf16, 32MB (reused as O')
    us*    Gt  = (us*)(ws + (size_t)100663296);            // [D][D] bf16
    us*    Wkb = (us*)(ws + (size_t)101187584);            // [D][D] bf16
    float* u   = (float*)(ws + (size_t)101711872);         // [D] fp32

    k_prep_x<<<dim3(8, 32, 16), 256, 0, stream>>>(seq, Xb, Xbt);
    k_prepG<<<dim3(8, 8), 256, 0, stream>>>(Wv, Wq, Gt);
    k_prepU<<<1, 512, 0, stream>>>(Wq, bv, u);
    k_prepW<<<256, 256, 0, stream>>>(Wk, Wkb);

    k_gemm<0><<<dim3(256, 4), 256, 0, stream>>>(Xb, Gt, u, (void*)Vtb);   // Vt = X*G + u
    k_attn<<<512, 512, 0, stream>>>(Vtb, Xb, Xbt, Vtb);                   // O' over Vt
    k_gemm<1><<<dim3(256, 4), 256, 0, stream>>>(Vtb, Wkb, bk, d_out);     // out = O'*Wk^T + bk
}